// Round 6
// baseline (586.037 us; speedup 1.0000x reference)
//
#include <hip/hip_runtime.h>
#include <hip/hip_bf16.h>
#include <stdint.h>

#define NN 50000
#define NE 800000
#define NR 16
#define NP (NN * NR)                 // 800000 (dst,rel) bins
#define NB1 ((NP + 255) / 256)       // 3125
#define NTILES ((NN + 127) / 128)    // 391
#define NWG_T (NTILES * 17)          // 6647 transform blocks

typedef unsigned short u16;
typedef unsigned int u32;

typedef __bf16 bf16x8 __attribute__((ext_vector_type(8)));
typedef __bf16 bf16x2 __attribute__((ext_vector_type(2)));
typedef float f32x4 __attribute__((ext_vector_type(4)));

__device__ __forceinline__ u16 f2bf(float f) {
  u32 u = __float_as_uint(f);
  u = u + 0x7FFFu + ((u >> 16) & 1u);
  return (u16)(u >> 16);
}

__device__ __forceinline__ u32 pk2bf(float x, float y) {
#if __has_builtin(__builtin_amdgcn_cvt_pk_bf16_f32)
  bf16x2 r = __builtin_amdgcn_cvt_pk_bf16_f32(x, y);
  union { bf16x2 v; u32 u; } c;
  c.v = r;
  return c.u;
#else
  return (u32)f2bf(x) | ((u32)f2bf(y) << 16);
#endif
}

__device__ __forceinline__ float bflo(u32 w) { return __uint_as_float(w << 16); }
__device__ __forceinline__ float bfhi(u32 w) { return __uint_as_float(w & 0xFFFF0000u); }

// ---------------- edge sort by (dst, rel) — counting sort over NP bins ----------------
__global__ void hist_kernel(const int* __restrict__ dst, const int* __restrict__ rel,
                            int* __restrict__ counts) {
  int e = blockIdx.x * 256 + threadIdx.x;
  if (e < NE) atomicAdd(&counts[dst[e] * NR + rel[e]], 1);
}

__global__ void scan_partial(const int* __restrict__ counts, int* __restrict__ bsum) {
  __shared__ int buf[256];
  int t = threadIdx.x;
  int i = blockIdx.x * 256 + t;
  int v = (i < NP) ? counts[i] : 0;
  buf[t] = v;
  __syncthreads();
  for (int off = 1; off < 256; off <<= 1) {
    int x = buf[t];
    int y = (t >= off) ? buf[t - off] : 0;
    __syncthreads();
    buf[t] = x + y;
    __syncthreads();
  }
  if (t == 255) bsum[blockIdx.x] = buf[255];
}

// single block, 1024 threads, 4-serial each: scans NB1 (<=4096) block sums
__global__ void scan_mid(const int* __restrict__ bsum, int* __restrict__ boff,
                         int* __restrict__ total_out) {
  __shared__ int buf[1024];
  int t = threadIdx.x;
  int v[4];
  int sum = 0;
#pragma unroll
  for (int i = 0; i < 4; ++i) {
    int idx = t * 4 + i;
    v[i] = (idx < NB1) ? bsum[idx] : 0;
    sum += v[i];
  }
  buf[t] = sum;
  __syncthreads();
  for (int off = 1; off < 1024; off <<= 1) {
    int x = buf[t];
    int y = (t >= off) ? buf[t - off] : 0;
    __syncthreads();
    buf[t] = x + y;
    __syncthreads();
  }
  int excl = buf[t] - sum;
#pragma unroll
  for (int i = 0; i < 4; ++i) {
    int idx = t * 4 + i;
    if (idx < NB1) { boff[idx] = excl; excl += v[i]; }
  }
  if (t == 1023) *total_out = buf[1023];
}

__global__ void scan_final(const int* __restrict__ counts, const int* __restrict__ boff,
                           int* __restrict__ starts, int* __restrict__ cursor) {
  __shared__ int buf[256];
  int t = threadIdx.x;
  int i = blockIdx.x * 256 + t;
  int v = (i < NP) ? counts[i] : 0;
  buf[t] = v;
  __syncthreads();
  for (int off = 1; off < 256; off <<= 1) {
    int x = buf[t];
    int y = (t >= off) ? buf[t - off] : 0;
    __syncthreads();
    buf[t] = x + y;
    __syncthreads();
  }
  int s = boff[blockIdx.x] + buf[t] - v;
  if (i < NP) {
    starts[i] = s;
    cursor[i] = s;
  }
}

// rowidx[pos] = rel*NN + src  (indexes BOTH gates[r][n] and th[r][n][:])
__global__ void scatter_kernel(const int* __restrict__ src, const int* __restrict__ dst,
                               const int* __restrict__ rel, const float* __restrict__ norm,
                               int* __restrict__ cursor, u32* __restrict__ rowidx,
                               float* __restrict__ norm_s) {
  int e = blockIdx.x * 256 + threadIdx.x;
  if (e < NE) {
    int d = dst[e];
    int r = rel[e];
    int pos = atomicAdd(&cursor[d * NR + r], 1);
    rowidx[pos] = (u32)(r * NN + src[e]);
    norm_s[pos] = norm[e];
  }
}

// ---------------- weight convert: Wt[mat][d][k] = bf16(W[mat][k][d]) ----------------
// mats 0..15 = w0 rels, 16 = lw0, 17..32 = w1 rels, 33 = lw1
__global__ void convert_wt(const float* __restrict__ w0, const float* __restrict__ lw0,
                           const float* __restrict__ w1, const float* __restrict__ lw1,
                           u16* __restrict__ Wt) {
  int m = blockIdx.y;
  int idx = blockIdx.x * 256 + threadIdx.x; // 0..16383
  int d = idx >> 7, k = idx & 127;
  const float* s;
  if (m < 16) s = w0 + (size_t)m * 16384;
  else if (m == 16) s = lw0;
  else if (m < 33) s = w1 + (size_t)(m - 17) * 16384;
  else s = lw1;
  Wt[(size_t)m * 16384 + idx] = f2bf(s[k * 128 + d]);
}

// ---------------- h f32 -> bf16 (layer 0 input only) ----------------
__global__ void hconv_kernel(const float* __restrict__ h, u16* __restrict__ hbf) {
  int i = blockIdx.x * 256 + threadIdx.x; // float4 index
  float4 v = ((const float4*)h)[i];
  ushort4 u;
  u.x = f2bf(v.x); u.y = f2bf(v.y); u.z = f2bf(v.z); u.w = f2bf(v.w);
  ((ushort4*)hbf)[i] = u;
}

// ---------------- gate table: gates[r][n] = sigmoid(hbf[n] . gw[r]) ----------------
__global__ void gates_kernel(const u16* __restrict__ hbf, const float* __restrict__ gw,
                             float* __restrict__ gates) {
  __shared__ float hs[16 * 132];
  __shared__ float gws[16 * 132];
  int t = threadIdx.x;
  int n0 = blockIdx.x * 16;
#pragma unroll
  for (int i = 0; i < 2; ++i) {
    int f = t + 256 * i;            // 0..511
    int row = f >> 5, c4 = (f & 31) * 4;
    ushort4 u = *(const ushort4*)&hbf[(size_t)(n0 + row) * 128 + c4];
    hs[row * 132 + c4 + 0] = __uint_as_float((u32)u.x << 16);
    hs[row * 132 + c4 + 1] = __uint_as_float((u32)u.y << 16);
    hs[row * 132 + c4 + 2] = __uint_as_float((u32)u.z << 16);
    hs[row * 132 + c4 + 3] = __uint_as_float((u32)u.w << 16);
    *(float4*)&gws[row * 132 + c4] = *(const float4*)&gw[row * 128 + c4];
  }
  __syncthreads();
  int nl = t >> 4, r = t & 15;
  float s = 0.f;
#pragma unroll 8
  for (int k = 0; k < 128; ++k) s += hs[nl * 132 + k] * gws[r * 132 + k];
  gates[r * NN + n0 + nl] = 1.f / (1.f + __expf(-s));
}

// ---------------- per-edge coefficient: coef[e] = gate[rowidx] * norm ----------------
__global__ void coef_kernel(const u32* __restrict__ rowidx,
                            const float* __restrict__ norm_s,
                            const float* __restrict__ gates, float* __restrict__ coef) {
  int e = blockIdx.x * 256 + threadIdx.x;
  if (e < NE) coef[e] = gates[rowidx[e]] * norm_s[e];
}

// ---------------- transform v2: th[m][n][:] = hbf @ W_m for m = 0..16 ----------------
// Round-4 issues: Occ 19.7% (68KB LDS -> 2 blocks/CU), hbf re-fetched ~8x (108 MB).
// v2: (a) no Ws LDS — W fragments straight from global (L2-hot 1.1MB) with 1-phase
// register prefetch; LDS 34.8KB. (b) 512-thread blocks, 8 waves x (64d x 32n): acc=32
// VGPR, ~90 live, lb(512,4) caps 128 -> no spill, 16 waves/CU. (c) bijective chunked
// XCD swizzle: the 17 blocks sharing one hbf tile run consecutively on one XCD ->
// tile fetched from HBM once, L2-served 16/17 times.
__global__ __launch_bounds__(512, 4)
void transform_kernel(const u16* __restrict__ hbf, const u16* __restrict__ Wtbase,
                      u16* __restrict__ th) {
  __shared__ u16 As[128 * 136];     // h tile, pad +8
  int orig = blockIdx.x;
  int qq = NWG_T / 8, rr = NWG_T % 8;           // 830, 7
  int xcd = orig & 7, idx = orig >> 3;
  int wgid = (xcd < rr ? xcd * (qq + 1) : rr * (qq + 1) + (xcd - rr) * qq) + idx;
  int tile = wgid / 17, m = wgid % 17;          // 16 = self loop
  int n0 = tile * 128;
  const u16* wmat = Wtbase + (size_t)m * 16384;

  int t = threadIdx.x;
  int wave = t >> 6, lane = t & 63;
  int wd = (wave & 1) * 64;         // wave owns d rows [wd, wd+64)
  int wn = (wave >> 1) * 32;        // wave owns n cols [wn, wn+32)
  int mrow = lane & 15, quad = lane >> 4;

  // stage h tile (128 rows x 256B), 4 uint4 per thread
#pragma unroll
  for (int i = 0; i < 4; ++i) {
    int u8i = t + 512 * i;          // 0..2047 uint4 slots = 128 rows x 16
    int row = u8i >> 4, c8 = (u8i & 15) * 8;
    int n = n0 + row;
    int nc = n < NN ? n : NN - 1;   // clamp; garbage rows never stored
    *(uint4*)&As[row * 136 + c8] = *(const uint4*)&hbf[(size_t)nc * 128 + c8];
  }
  __syncthreads();

  f32x4 acc[4][2];
#pragma unroll
  for (int i = 0; i < 4; ++i)
#pragma unroll
    for (int j = 0; j < 2; ++j) acc[i][j] = (f32x4){0.f, 0.f, 0.f, 0.f};

  bf16x8 faA[4], faB[4];

#define LDFA(F, KK)                                                           \
  _Pragma("unroll")                                                           \
  for (int i2 = 0; i2 < 4; ++i2)                                              \
    F[i2] = *(const bf16x8*)&wmat[(wd + i2 * 16 + mrow) * 128 +               \
                                  (KK) * 32 + quad * 8];

#define DOK(F, KK)                                                            \
  {                                                                           \
    int k0 = (KK) * 32 + quad * 8;                                            \
    bf16x8 fb[2];                                                             \
    _Pragma("unroll")                                                         \
    for (int j2 = 0; j2 < 2; ++j2)                                            \
      fb[j2] = *(const bf16x8*)&As[(wn + j2 * 16 + mrow) * 136 + k0];         \
    _Pragma("unroll")                                                         \
    for (int i2 = 0; i2 < 4; ++i2)                                            \
      _Pragma("unroll")                                                       \
      for (int j2 = 0; j2 < 2; ++j2)                                          \
        acc[i2][j2] = __builtin_amdgcn_mfma_f32_16x16x32_bf16(                \
            F[i2], fb[j2], acc[i2][j2], 0, 0, 0);                             \
  }

  LDFA(faA, 0)
  LDFA(faB, 1)
  DOK(faA, 0)
  LDFA(faA, 2)
  DOK(faB, 1)
  LDFA(faB, 3)
  DOK(faA, 2)
  DOK(faB, 3)

  // epilogue: lane owns node n = n0+wn+j2*16+mrow, d = wd+i2*16+quad*4 .. +3
#pragma unroll
  for (int j2 = 0; j2 < 2; ++j2) {
    int n = n0 + wn + j2 * 16 + mrow;
    if (n < NN) {
#pragma unroll
      for (int i2 = 0; i2 < 4; ++i2) {
        int d0 = wd + i2 * 16 + quad * 4;
        uint2 st;
        st.x = pk2bf(acc[i2][j2][0], acc[i2][j2][1]);
        st.y = pk2bf(acc[i2][j2][2], acc[i2][j2][3]);
        *(uint2*)&th[((size_t)m * NN + n) * 128 + d0] = st;
      }
    }
  }
#undef LDFA
#undef DOK
}

// ---------------- gatheradd: out[v] = sum coef*th[rowidx] + th_self[v] + b ----------
// 12500 blocks x 4 waves, 1 node/wave. Batch-16 (avg degree = 16 -> typically ONE
// vmcnt wait per node; 16 outstanding 256B gathers vs ~900cy HBM/L3 latency).
// Invalid slots clamp the index (valid memory) and zero the coefficient.
template <int LAYER>
__global__ __launch_bounds__(256)
void gatheradd_kernel(const u16* __restrict__ th, const u32* __restrict__ rowidx,
                      const float* __restrict__ coef, const int* __restrict__ starts,
                      const float* __restrict__ bias,
                      u16* __restrict__ hb_out, float* __restrict__ fout) {
  const u32* th32 = (const u32*)th;
  int wave = threadIdx.x >> 6;
  u32 lane = (u32)(threadIdx.x & 63);
  int v = blockIdx.x * 4 + wave;    // NN = 12500*4 -> always < NN
  int s = starts[v * NR];
  int e = starts[v * NR + NR];      // starts[NP] sentinel = NE for v = NN-1
  float a0 = 0.f, a1 = 0.f;
  for (int j = s; j < e; j += 16) {
    u32 ri[16];
    float cf[16];
#pragma unroll
    for (int i = 0; i < 16; ++i) {
      int ii = (j + i < e) ? (j + i) : (e - 1);
      ri[i] = rowidx[ii];
      cf[i] = (j + i < e) ? coef[ii] : 0.f;
    }
    u32 w[16];
#pragma unroll
    for (int i = 0; i < 16; ++i) w[i] = th32[ri[i] * 64u + lane];
#pragma unroll
    for (int i = 0; i < 16; ++i) {
      a0 = fmaf(cf[i], bflo(w[i]), a0);
      a1 = fmaf(cf[i], bfhi(w[i]), a1);
    }
  }
  // self-loop (th mat 16) + bias
  u32 ts = th32[((u32)(16 * NN) + (u32)v) * 64u + lane];
  float2 bv = *(const float2*)&bias[lane * 2u];
  a0 += bflo(ts) + bv.x;
  a1 += bfhi(ts) + bv.y;
  if (LAYER == 0) {
    a0 = fmaxf(a0, 0.f);
    a1 = fmaxf(a1, 0.f);
    ((u32*)hb_out)[(size_t)v * 64 + lane] = pk2bf(a0, a1);
  } else {
    *(float2*)&fout[(size_t)v * 128 + lane * 2u] = make_float2(a0, a1);
  }
}

// ---------------- host ----------------
extern "C" void kernel_launch(void* const* d_in, const int* in_sizes, int n_in,
                              void* d_out, int out_size, void* d_ws, size_t ws_size,
                              hipStream_t stream) {
  const float* h0   = (const float*)d_in[0];
  const float* norm = (const float*)d_in[1];
  const float* w0   = (const float*)d_in[2];
  const float* b0   = (const float*)d_in[3];
  const float* lw0  = (const float*)d_in[4];
  const float* gw0  = (const float*)d_in[5];
  const float* w1   = (const float*)d_in[6];
  const float* b1   = (const float*)d_in[7];
  const float* lw1  = (const float*)d_in[8];
  const float* gw1  = (const float*)d_in[9];
  const int*   src  = (const int*)d_in[10];
  const int*   dst  = (const int*)d_in[11];
  const int*   rel  = (const int*)d_in[12];
  float* out = (float*)d_out;

  char* p = (char*)d_ws;
  auto alloc = [&](size_t bytes) -> void* {
    void* q = (void*)p;
    p += (bytes + 255) & ~(size_t)255;
    return q;
  };
  u16*   Wt     = (u16*)alloc((size_t)34 * 16384 * 2);        // 1.1 MB
  float* gates  = (float*)alloc((size_t)NR * NN * 4);         // 3.2 MB
  u16*   hbf    = (u16*)alloc((size_t)NN * 128 * 2);          // 12.8 MB (h0 then h1)
  int*   counts = (int*)alloc((size_t)NP * 4);                // 3.2 MB
  int*   cursor = (int*)alloc((size_t)NP * 4);                // 3.2 MB
  int*   starts = (int*)alloc((size_t)(NP + 1) * 4);          // 3.2 MB
  int*   bsum   = (int*)alloc((size_t)NB1 * 4);
  int*   boff   = (int*)alloc((size_t)NB1 * 4);
  u32*   rowidx = (u32*)alloc((size_t)NE * 4);                // 3.2 MB
  u16*   th     = (u16*)alloc((size_t)17 * NN * 128 * 2);     // 217.6 MB
  // aliases over dead buffers:
  float* norm_s = (float*)counts;   // counts dead after scan_final; written by scatter
  float* coef   = (float*)cursor;   // cursor dead after scatter; written by coef_kernel

  // ---- sort edges by (dst, rel) — shared by both layers ----
  hipMemsetAsync(counts, 0, (size_t)NP * 4, stream);
  hist_kernel<<<NE / 256, 256, 0, stream>>>(dst, rel, counts);
  scan_partial<<<NB1, 256, 0, stream>>>(counts, bsum);
  scan_mid<<<1, 1024, 0, stream>>>(bsum, boff, starts + NP);
  scan_final<<<NB1, 256, 0, stream>>>(counts, boff, starts, cursor);
  scatter_kernel<<<NE / 256, 256, 0, stream>>>(src, dst, rel, norm, cursor,
                                               rowidx, norm_s);
  convert_wt<<<dim3(64, 34), 256, 0, stream>>>(w0, lw0, w1, lw1, Wt);
  hconv_kernel<<<NN * 32 / 256, 256, 0, stream>>>(h0, hbf);

  // ---- layer 0 (relu, bf16 output back into hbf) ----
  gates_kernel<<<NN / 16, 256, 0, stream>>>(hbf, gw0, gates);
  coef_kernel<<<(NE + 255) / 256, 256, 0, stream>>>(rowidx, norm_s, gates, coef);
  transform_kernel<<<NWG_T, 512, 0, stream>>>(hbf, Wt, th);
  gatheradd_kernel<0><<<NN / 4, 256, 0, stream>>>(th, rowidx, coef, starts, b0,
                                                  hbf, nullptr);

  // ---- layer 1 (no relu, f32 output) ----
  gates_kernel<<<NN / 16, 256, 0, stream>>>(hbf, gw1, gates);
  coef_kernel<<<(NE + 255) / 256, 256, 0, stream>>>(rowidx, norm_s, gates, coef);
  transform_kernel<<<NWG_T, 512, 0, stream>>>(hbf, Wt + (size_t)17 * 16384, th);
  gatheradd_kernel<1><<<NN / 4, 256, 0, stream>>>(th, rowidx, coef, starts, b1,
                                                  nullptr, out);
}

// Round 7
// 541.303 us; speedup vs baseline: 1.0826x; 1.0826x over previous
//
#include <hip/hip_runtime.h>
#include <hip/hip_bf16.h>
#include <stdint.h>

#define NN 50000
#define NE 800000
#define NR 16
#define NP (NN * NR)                 // 800000 (dst,rel) bins
#define NB1 ((NP + 255) / 256)       // 3125
#define NTILES ((NN + 127) / 128)    // 391
#define NWG_T (NTILES * 17)          // 6647 transform blocks

typedef unsigned short u16;
typedef unsigned int u32;

typedef __bf16 bf16x8 __attribute__((ext_vector_type(8)));
typedef __bf16 bf16x2 __attribute__((ext_vector_type(2)));
typedef float f32x4 __attribute__((ext_vector_type(4)));

__device__ __forceinline__ u16 f2bf(float f) {
  u32 u = __float_as_uint(f);
  u = u + 0x7FFFu + ((u >> 16) & 1u);
  return (u16)(u >> 16);
}

__device__ __forceinline__ u32 pk2bf(float x, float y) {
#if __has_builtin(__builtin_amdgcn_cvt_pk_bf16_f32)
  bf16x2 r = __builtin_amdgcn_cvt_pk_bf16_f32(x, y);
  union { bf16x2 v; u32 u; } c;
  c.v = r;
  return c.u;
#else
  return (u32)f2bf(x) | ((u32)f2bf(y) << 16);
#endif
}

__device__ __forceinline__ float bflo(u32 w) { return __uint_as_float(w << 16); }
__device__ __forceinline__ float bfhi(u32 w) { return __uint_as_float(w & 0xFFFF0000u); }

// ---------------- edge sort by (dst, rel) — counting sort over NP bins ----------------
__global__ void hist_kernel(const int* __restrict__ dst, const int* __restrict__ rel,
                            int* __restrict__ counts) {
  int e = blockIdx.x * 256 + threadIdx.x;
  if (e < NE) atomicAdd(&counts[dst[e] * NR + rel[e]], 1);
}

__global__ void scan_partial(const int* __restrict__ counts, int* __restrict__ bsum) {
  __shared__ int buf[256];
  int t = threadIdx.x;
  int i = blockIdx.x * 256 + t;
  int v = (i < NP) ? counts[i] : 0;
  buf[t] = v;
  __syncthreads();
  for (int off = 1; off < 256; off <<= 1) {
    int x = buf[t];
    int y = (t >= off) ? buf[t - off] : 0;
    __syncthreads();
    buf[t] = x + y;
    __syncthreads();
  }
  if (t == 255) bsum[blockIdx.x] = buf[255];
}

// single block, 1024 threads, 4-serial each: scans NB1 (<=4096) block sums
__global__ void scan_mid(const int* __restrict__ bsum, int* __restrict__ boff,
                         int* __restrict__ total_out) {
  __shared__ int buf[1024];
  int t = threadIdx.x;
  int v[4];
  int sum = 0;
#pragma unroll
  for (int i = 0; i < 4; ++i) {
    int idx = t * 4 + i;
    v[i] = (idx < NB1) ? bsum[idx] : 0;
    sum += v[i];
  }
  buf[t] = sum;
  __syncthreads();
  for (int off = 1; off < 1024; off <<= 1) {
    int x = buf[t];
    int y = (t >= off) ? buf[t - off] : 0;
    __syncthreads();
    buf[t] = x + y;
    __syncthreads();
  }
  int excl = buf[t] - sum;
#pragma unroll
  for (int i = 0; i < 4; ++i) {
    int idx = t * 4 + i;
    if (idx < NB1) { boff[idx] = excl; excl += v[i]; }
  }
  if (t == 1023) *total_out = buf[1023];
}

__global__ void scan_final(const int* __restrict__ counts, const int* __restrict__ boff,
                           int* __restrict__ starts, int* __restrict__ cursor) {
  __shared__ int buf[256];
  int t = threadIdx.x;
  int i = blockIdx.x * 256 + t;
  int v = (i < NP) ? counts[i] : 0;
  buf[t] = v;
  __syncthreads();
  for (int off = 1; off < 256; off <<= 1) {
    int x = buf[t];
    int y = (t >= off) ? buf[t - off] : 0;
    __syncthreads();
    buf[t] = x + y;
    __syncthreads();
  }
  int s = boff[blockIdx.x] + buf[t] - v;
  if (i < NP) {
    starts[i] = s;
    cursor[i] = s;
  }
}

// rowidx[pos] = rel*NN + src  (indexes BOTH gates[r][n] and th[r][n][:])
__global__ void scatter_kernel(const int* __restrict__ src, const int* __restrict__ dst,
                               const int* __restrict__ rel, const float* __restrict__ norm,
                               int* __restrict__ cursor, u32* __restrict__ rowidx,
                               float* __restrict__ norm_s) {
  int e = blockIdx.x * 256 + threadIdx.x;
  if (e < NE) {
    int d = dst[e];
    int r = rel[e];
    int pos = atomicAdd(&cursor[d * NR + r], 1);
    rowidx[pos] = (u32)(r * NN + src[e]);
    norm_s[pos] = norm[e];
  }
}

// ---------------- weight convert: Wt[mat][d][k] = bf16(W[mat][k][d]) ----------------
// mats 0..15 = w0 rels, 16 = lw0, 17..32 = w1 rels, 33 = lw1
__global__ void convert_wt(const float* __restrict__ w0, const float* __restrict__ lw0,
                           const float* __restrict__ w1, const float* __restrict__ lw1,
                           u16* __restrict__ Wt) {
  int m = blockIdx.y;
  int idx = blockIdx.x * 256 + threadIdx.x; // 0..16383
  int d = idx >> 7, k = idx & 127;
  const float* s;
  if (m < 16) s = w0 + (size_t)m * 16384;
  else if (m == 16) s = lw0;
  else if (m < 33) s = w1 + (size_t)(m - 17) * 16384;
  else s = lw1;
  Wt[(size_t)m * 16384 + idx] = f2bf(s[k * 128 + d]);
}

// ---------------- h f32 -> bf16 (layer 0 input only) ----------------
__global__ void hconv_kernel(const float* __restrict__ h, u16* __restrict__ hbf) {
  int i = blockIdx.x * 256 + threadIdx.x; // float4 index
  float4 v = ((const float4*)h)[i];
  ushort4 u;
  u.x = f2bf(v.x); u.y = f2bf(v.y); u.z = f2bf(v.z); u.w = f2bf(v.w);
  ((ushort4*)hbf)[i] = u;
}

// ---------------- gate table: gates[r][n] = sigmoid(hbf[n] . gw[r]) ----------------
__global__ void gates_kernel(const u16* __restrict__ hbf, const float* __restrict__ gw,
                             float* __restrict__ gates) {
  __shared__ float hs[16 * 132];
  __shared__ float gws[16 * 132];
  int t = threadIdx.x;
  int n0 = blockIdx.x * 16;
#pragma unroll
  for (int i = 0; i < 2; ++i) {
    int f = t + 256 * i;            // 0..511
    int row = f >> 5, c4 = (f & 31) * 4;
    ushort4 u = *(const ushort4*)&hbf[(size_t)(n0 + row) * 128 + c4];
    hs[row * 132 + c4 + 0] = __uint_as_float((u32)u.x << 16);
    hs[row * 132 + c4 + 1] = __uint_as_float((u32)u.y << 16);
    hs[row * 132 + c4 + 2] = __uint_as_float((u32)u.z << 16);
    hs[row * 132 + c4 + 3] = __uint_as_float((u32)u.w << 16);
    *(float4*)&gws[row * 132 + c4] = *(const float4*)&gw[row * 128 + c4];
  }
  __syncthreads();
  int nl = t >> 4, r = t & 15;
  float s = 0.f;
#pragma unroll 8
  for (int k = 0; k < 128; ++k) s += hs[nl * 132 + k] * gws[r * 132 + k];
  gates[r * NN + n0 + nl] = 1.f / (1.f + __expf(-s));
}

// ---------------- per-edge coefficient: coef[e] = gate[rowidx] * norm ----------------
__global__ void coef_kernel(const u32* __restrict__ rowidx,
                            const float* __restrict__ norm_s,
                            const float* __restrict__ gates, float* __restrict__ coef) {
  int e = blockIdx.x * 256 + threadIdx.x;
  if (e < NE) coef[e] = gates[rowidx[e]] * norm_s[e];
}

// ---------------- transform v3: th[m][n][:] = hbf @ W_m for m = 0..16 ----------------
// Round-5 diagnosis: write-throughput-bound at 1.57 TB/s because the MFMA epilogue
// stores 8B/lane scattered (16 rows x 32B partial lines per store). v3 keeps the
// compute + XCD swizzle (FETCH 8.5 MB) and fixes ONLY the store path: epilogue ->
// Os LDS tile, one barrier, then contiguous streaming copy-out (16B/lane, 1KB/wave,
// 32KB/block) matching the m13 6.3 TB/s store pattern.
__global__ __launch_bounds__(512, 2)
void transform_kernel(const u16* __restrict__ hbf, const u16* __restrict__ Wtbase,
                      u16* __restrict__ th) {
  __shared__ u16 As[128 * 136];     // h tile, pad +8
  __shared__ u16 Os[128 * 136];     // output staging tile
  int orig = blockIdx.x;
  int qq = NWG_T / 8, rr = NWG_T % 8;           // 830, 7
  int xcd = orig & 7, idx = orig >> 3;
  int wgid = (xcd < rr ? xcd * (qq + 1) : rr * (qq + 1) + (xcd - rr) * qq) + idx;
  int tile = wgid / 17, m = wgid % 17;          // 16 = self loop
  int n0 = tile * 128;
  const u16* wmat = Wtbase + (size_t)m * 16384;

  int t = threadIdx.x;
  int wave = t >> 6, lane = t & 63;
  int wd = (wave & 1) * 64;         // wave owns d rows [wd, wd+64)
  int wn = (wave >> 1) * 32;        // wave owns n cols [wn, wn+32)
  int mrow = lane & 15, quad = lane >> 4;

  // stage h tile (128 rows x 256B), 4 uint4 per thread
#pragma unroll
  for (int i = 0; i < 4; ++i) {
    int u8i = t + 512 * i;          // 0..2047 uint4 slots = 128 rows x 16
    int row = u8i >> 4, c8 = (u8i & 15) * 8;
    int n = n0 + row;
    int nc = n < NN ? n : NN - 1;   // clamp; garbage rows never stored
    *(uint4*)&As[row * 136 + c8] = *(const uint4*)&hbf[(size_t)nc * 128 + c8];
  }
  __syncthreads();

  f32x4 acc[4][2];
#pragma unroll
  for (int i = 0; i < 4; ++i)
#pragma unroll
    for (int j = 0; j < 2; ++j) acc[i][j] = (f32x4){0.f, 0.f, 0.f, 0.f};

  bf16x8 faA[4], faB[4];

#define LDFA(F, KK)                                                           \
  _Pragma("unroll")                                                           \
  for (int i2 = 0; i2 < 4; ++i2)                                              \
    F[i2] = *(const bf16x8*)&wmat[(wd + i2 * 16 + mrow) * 128 +               \
                                  (KK) * 32 + quad * 8];

#define DOK(F, KK)                                                            \
  {                                                                           \
    int k0 = (KK) * 32 + quad * 8;                                            \
    bf16x8 fb[2];                                                             \
    _Pragma("unroll")                                                         \
    for (int j2 = 0; j2 < 2; ++j2)                                            \
      fb[j2] = *(const bf16x8*)&As[(wn + j2 * 16 + mrow) * 136 + k0];         \
    _Pragma("unroll")                                                         \
    for (int i2 = 0; i2 < 4; ++i2)                                            \
      _Pragma("unroll")                                                       \
      for (int j2 = 0; j2 < 2; ++j2)                                          \
        acc[i2][j2] = __builtin_amdgcn_mfma_f32_16x16x32_bf16(                \
            F[i2], fb[j2], acc[i2][j2], 0, 0, 0);                             \
  }

  LDFA(faA, 0)
  LDFA(faB, 1)
  DOK(faA, 0)
  LDFA(faA, 2)
  DOK(faB, 1)
  LDFA(faB, 3)
  DOK(faA, 2)
  DOK(faB, 3)

  // epilogue pt1: fragments -> Os (8B/lane, 272B row stride -> 2-way alias = free)
#pragma unroll
  for (int j2 = 0; j2 < 2; ++j2) {
    int nl = wn + j2 * 16 + mrow;
#pragma unroll
    for (int i2 = 0; i2 < 4; ++i2) {
      int d0 = wd + i2 * 16 + quad * 4;
      uint2 st;
      st.x = pk2bf(acc[i2][j2][0], acc[i2][j2][1]);
      st.y = pk2bf(acc[i2][j2][2], acc[i2][j2][3]);
      *(uint2*)&Os[nl * 136 + d0] = st;
    }
  }
  __syncthreads();

  // epilogue pt2: streaming copy-out — 16B/lane, each wave 4 full rows = 1KB
  // contiguous, block streams 32KB of full cache lines.
#pragma unroll
  for (int i = 0; i < 4; ++i) {
    int u8i = t + 512 * i;          // 0..2047 uint4 slots = 128 rows x 16
    int row = u8i >> 4, c8 = (u8i & 15) * 8;
    int n = n0 + row;
    if (n < NN)
      *(uint4*)&th[((size_t)m * NN + n) * 128 + c8] = *(const uint4*)&Os[row * 136 + c8];
  }
#undef LDFA
#undef DOK
}

// ---------------- gatheradd: out[v] = sum coef*th[rowidx] + th_self[v] + b ----------
// 12500 blocks x 4 waves, 1 node/wave. Batch-16 (avg degree = 16 -> typically ONE
// vmcnt wait per node; 16 outstanding 256B gathers vs ~900cy HBM/L3 latency).
// Invalid slots clamp the index (valid memory) and zero the coefficient.
template <int LAYER>
__global__ __launch_bounds__(256)
void gatheradd_kernel(const u16* __restrict__ th, const u32* __restrict__ rowidx,
                      const float* __restrict__ coef, const int* __restrict__ starts,
                      const float* __restrict__ bias,
                      u16* __restrict__ hb_out, float* __restrict__ fout) {
  const u32* th32 = (const u32*)th;
  int wave = threadIdx.x >> 6;
  u32 lane = (u32)(threadIdx.x & 63);
  int v = blockIdx.x * 4 + wave;    // NN = 12500*4 -> always < NN
  int s = starts[v * NR];
  int e = starts[v * NR + NR];      // starts[NP] sentinel = NE for v = NN-1
  float a0 = 0.f, a1 = 0.f;
  for (int j = s; j < e; j += 16) {
    u32 ri[16];
    float cf[16];
#pragma unroll
    for (int i = 0; i < 16; ++i) {
      int ii = (j + i < e) ? (j + i) : (e - 1);
      ri[i] = rowidx[ii];
      cf[i] = (j + i < e) ? coef[ii] : 0.f;
    }
    u32 w[16];
#pragma unroll
    for (int i = 0; i < 16; ++i) w[i] = th32[ri[i] * 64u + lane];
#pragma unroll
    for (int i = 0; i < 16; ++i) {
      a0 = fmaf(cf[i], bflo(w[i]), a0);
      a1 = fmaf(cf[i], bfhi(w[i]), a1);
    }
  }
  // self-loop (th mat 16) + bias
  u32 ts = th32[((u32)(16 * NN) + (u32)v) * 64u + lane];
  float2 bv = *(const float2*)&bias[lane * 2u];
  a0 += bflo(ts) + bv.x;
  a1 += bfhi(ts) + bv.y;
  if (LAYER == 0) {
    a0 = fmaxf(a0, 0.f);
    a1 = fmaxf(a1, 0.f);
    ((u32*)hb_out)[(size_t)v * 64 + lane] = pk2bf(a0, a1);
  } else {
    *(float2*)&fout[(size_t)v * 128 + lane * 2u] = make_float2(a0, a1);
  }
}

// ---------------- host ----------------
extern "C" void kernel_launch(void* const* d_in, const int* in_sizes, int n_in,
                              void* d_out, int out_size, void* d_ws, size_t ws_size,
                              hipStream_t stream) {
  const float* h0   = (const float*)d_in[0];
  const float* norm = (const float*)d_in[1];
  const float* w0   = (const float*)d_in[2];
  const float* b0   = (const float*)d_in[3];
  const float* lw0  = (const float*)d_in[4];
  const float* gw0  = (const float*)d_in[5];
  const float* w1   = (const float*)d_in[6];
  const float* b1   = (const float*)d_in[7];
  const float* lw1  = (const float*)d_in[8];
  const float* gw1  = (const float*)d_in[9];
  const int*   src  = (const int*)d_in[10];
  const int*   dst  = (const int*)d_in[11];
  const int*   rel  = (const int*)d_in[12];
  float* out = (float*)d_out;

  char* p = (char*)d_ws;
  auto alloc = [&](size_t bytes) -> void* {
    void* q = (void*)p;
    p += (bytes + 255) & ~(size_t)255;
    return q;
  };
  u16*   Wt     = (u16*)alloc((size_t)34 * 16384 * 2);        // 1.1 MB
  float* gates  = (float*)alloc((size_t)NR * NN * 4);         // 3.2 MB
  u16*   hbf    = (u16*)alloc((size_t)NN * 128 * 2);          // 12.8 MB (h0 then h1)
  int*   counts = (int*)alloc((size_t)NP * 4);                // 3.2 MB
  int*   cursor = (int*)alloc((size_t)NP * 4);                // 3.2 MB
  int*   starts = (int*)alloc((size_t)(NP + 1) * 4);          // 3.2 MB
  int*   bsum   = (int*)alloc((size_t)NB1 * 4);
  int*   boff   = (int*)alloc((size_t)NB1 * 4);
  u32*   rowidx = (u32*)alloc((size_t)NE * 4);                // 3.2 MB
  u16*   th     = (u16*)alloc((size_t)17 * NN * 128 * 2);     // 217.6 MB
  // aliases over dead buffers:
  float* norm_s = (float*)counts;   // counts dead after scan_final; written by scatter
  float* coef   = (float*)cursor;   // cursor dead after scatter; written by coef_kernel

  // ---- sort edges by (dst, rel) — shared by both layers ----
  hipMemsetAsync(counts, 0, (size_t)NP * 4, stream);
  hist_kernel<<<NE / 256, 256, 0, stream>>>(dst, rel, counts);
  scan_partial<<<NB1, 256, 0, stream>>>(counts, bsum);
  scan_mid<<<1, 1024, 0, stream>>>(bsum, boff, starts + NP);
  scan_final<<<NB1, 256, 0, stream>>>(counts, boff, starts, cursor);
  scatter_kernel<<<NE / 256, 256, 0, stream>>>(src, dst, rel, norm, cursor,
                                               rowidx, norm_s);
  convert_wt<<<dim3(64, 34), 256, 0, stream>>>(w0, lw0, w1, lw1, Wt);
  hconv_kernel<<<NN * 32 / 256, 256, 0, stream>>>(h0, hbf);

  // ---- layer 0 (relu, bf16 output back into hbf) ----
  gates_kernel<<<NN / 16, 256, 0, stream>>>(hbf, gw0, gates);
  coef_kernel<<<(NE + 255) / 256, 256, 0, stream>>>(rowidx, norm_s, gates, coef);
  transform_kernel<<<NWG_T, 512, 0, stream>>>(hbf, Wt, th);
  gatheradd_kernel<0><<<NN / 4, 256, 0, stream>>>(th, rowidx, coef, starts, b0,
                                                  hbf, nullptr);

  // ---- layer 1 (no relu, f32 output) ----
  gates_kernel<<<NN / 16, 256, 0, stream>>>(hbf, gw1, gates);
  coef_kernel<<<(NE + 255) / 256, 256, 0, stream>>>(rowidx, norm_s, gates, coef);
  transform_kernel<<<NWG_T, 512, 0, stream>>>(hbf, Wt + (size_t)17 * 16384, th);
  gatheradd_kernel<1><<<NN / 4, 256, 0, stream>>>(th, rowidx, coef, starts, b1,
                                                  nullptr, out);
}